// Round 1
// baseline (1656.214 us; speedup 1.0000x reference)
//
#include <hip/hip_runtime.h>
#include <hip/hip_bf16.h>

// TemporalGNN: reference's GRU uses H0=zeros every step => R dead, steps independent.
// out[b,n,:] = relu( sum_t p_t * (1-Z)*Ht ) @ W_out + b_out
//   Z  = sigmoid( Y_t @ (Wg_z@Wl_z[:64]) + (bg_z@Wl_z[:64] + bl_z) )
//   Ht = tanh   ( Y_t @ (Wg_h@Wl_h[:64]) + (bg_h@Wl_h[:64] + bl_h) )
//   Y_t = normalized-adjacency aggregation of X[...,t] in F=32 space.

#define FDIM 32
#define TDIM 12
#define ODIM 64
#define BDIM 4

__global__ void k_count(const int* __restrict__ dst, int* __restrict__ counts, int E) {
    int e = blockIdx.x * 256 + threadIdx.x;
    if (e < E) atomicAdd(&counts[dst[e]], 1);
}

__global__ void k_scan(const int* __restrict__ counts, int* __restrict__ offsets,
                       float* __restrict__ dis, int N) {
    __shared__ int tmp[256];
    __shared__ int sCarry;
    int tid = threadIdx.x;
    if (tid == 0) sCarry = 0;
    __syncthreads();
    for (int base = 0; base < N; base += 256) {
        int i = base + tid;
        int v = (i < N) ? counts[i] : 0;
        tmp[tid] = v;
        __syncthreads();
        int sum = v;
        for (int off = 1; off < 256; off <<= 1) {
            int add = (tid >= off) ? tmp[tid - off] : 0;
            __syncthreads();
            sum += add;
            tmp[tid] = sum;
            __syncthreads();
        }
        int carry = sCarry;
        if (i < N) {
            offsets[i] = carry + sum - v;           // exclusive
            dis[i] = 1.0f / sqrtf((float)(v + 1));  // deg^{-1/2}, deg = indeg+1
        }
        __syncthreads();
        if (tid == 255) sCarry = carry + sum;
        __syncthreads();
    }
    if (tid == 0) offsets[N] = sCarry;
}

__global__ void k_scatter(const int* __restrict__ src, const int* __restrict__ dst,
                          const int* __restrict__ offsets, int* __restrict__ fill,
                          const float* __restrict__ dis,
                          int* __restrict__ csr_src, float* __restrict__ csr_norm, int E) {
    int e = blockIdx.x * 256 + threadIdx.x;
    if (e < E) {
        int s = src[e], d = dst[e];
        int pos = offsets[d] + atomicAdd(&fill[d], 1);
        csr_src[pos] = s;
        csr_norm[pos] = dis[s] * dis[d];
    }
}

// Fold Wg@Wl_top, biases, and softmax(att) once per launch.
__global__ void k_prep(const float* __restrict__ Wg_z, const float* __restrict__ bg_z,
                       const float* __restrict__ Wl_z, const float* __restrict__ bl_z,
                       const float* __restrict__ Wg_h, const float* __restrict__ bg_h,
                       const float* __restrict__ Wl_h, const float* __restrict__ bl_h,
                       const float* __restrict__ att,
                       float* __restrict__ Wz, float* __restrict__ bz,
                       float* __restrict__ Wh, float* __restrict__ bh,
                       float* __restrict__ probs) {
    int tid = threadIdx.x;
    for (int i = tid; i < FDIM * ODIM; i += 256) {
        int f = i >> 6, o = i & 63;
        float az = 0.f, ah = 0.f;
        for (int k = 0; k < ODIM; k++) {
            az += Wg_z[f * ODIM + k] * Wl_z[k * ODIM + o];
            ah += Wg_h[f * ODIM + k] * Wl_h[k * ODIM + o];
        }
        Wz[i] = az;
        Wh[i] = ah;
    }
    if (tid < ODIM) {
        float az = bl_z[tid], ah = bl_h[tid];
        for (int k = 0; k < ODIM; k++) {
            az += bg_z[k] * Wl_z[k * ODIM + tid];
            ah += bg_h[k] * Wl_h[k * ODIM + tid];
        }
        bz[tid] = az;
        bh[tid] = ah;
    }
    if (tid == 0) {
        float m = -1e30f;
        for (int t = 0; t < TDIM; t++) m = fmaxf(m, att[t]);
        float e[TDIM], s = 0.f;
        for (int t = 0; t < TDIM; t++) { e[t] = expf(att[t] - m); s += e[t]; }
        for (int t = 0; t < TDIM; t++) probs[t] = e[t] / s;
    }
}

// One workgroup per node n; 384 threads = 6 waves.
// Phase 1: aggregate all 4 batches' [F,T]=384-float rows (float4 gathers).
// Phase 2: GEMV 32->64 for z/h gates, all t at once, weights in registers.
// Phase 3: ReLU + 64->12 readout.
__global__ __launch_bounds__(384) void k_main(
    const float* __restrict__ X, const int* __restrict__ offsets,
    const int* __restrict__ csr_src, const float* __restrict__ csr_norm,
    const float* __restrict__ dis,
    const float* __restrict__ Wz, const float* __restrict__ bz,
    const float* __restrict__ Wh, const float* __restrict__ bh,
    const float* __restrict__ probs, const float* __restrict__ Wout,
    const float* __restrict__ bout, float* __restrict__ out, int N) {
    const int n = blockIdx.x;
    const int tid = threadIdx.x;

    __shared__ float sWz[FDIM * ODIM];
    __shared__ float sWh[FDIM * ODIM];
    __shared__ float4 sY4[BDIM][96];          // [b][f*T+t as float4]
    __shared__ float sAcc[BDIM][ODIM];
    __shared__ float sbz[ODIM], sbh[ODIM];
    __shared__ float sProbs[TDIM], sbout[TDIM];
    __shared__ float sWout[ODIM * TDIM];

    for (int i = tid; i < FDIM * ODIM; i += 384) { sWz[i] = Wz[i]; sWh[i] = Wh[i]; }
    for (int i = tid; i < ODIM * TDIM; i += 384) sWout[i] = Wout[i];
    if (tid < ODIM) { sbz[tid] = bz[tid]; sbh[tid] = bh[tid]; }
    if (tid < TDIM) { sProbs[tid] = probs[tid]; sbout[tid] = bout[tid]; }
    if (tid < BDIM * ODIM) ((float*)sAcc)[tid] = 0.f;

    const int beg = offsets[n], end = offsets[n + 1];
    const float dn = dis[n];
    const float snorm = dn * dn;

    // ---- Phase 1: aggregation (thread owns batch b, float4-chunk q) ----
    const int b = tid / 96;
    const int q = tid - b * 96;
    const float4* Xq = (const float4*)X;
    float4 y = Xq[(unsigned)(b * N + n) * 96u + q];
    y.x *= snorm; y.y *= snorm; y.z *= snorm; y.w *= snorm;
    for (int j = beg; j < end; j++) {
        int s = csr_src[j];
        float nm = csr_norm[j];
        float4 v = Xq[(unsigned)(b * N + s) * 96u + q];
        y.x += nm * v.x; y.y += nm * v.y; y.z += nm * v.z; y.w += nm * v.w;
    }
    sY4[b][q] = y;
    __syncthreads();

    // ---- Phase 2: gates. thread -> (o = tid&63, wave w = tid>>6, t in {w, w+6}) ----
    const int o = tid & 63;
    const int w = tid >> 6;
    float wzr[FDIM], whr[FDIM];
#pragma unroll
    for (int f = 0; f < FDIM; f++) {
        wzr[f] = sWz[f * ODIM + o];
        whr[f] = sWh[f * ODIM + o];
    }
    const int t0 = w, t1 = w + 6;
    const float p0 = sProbs[t0], p1 = sProbs[t1];
#pragma unroll
    for (int bb = 0; bb < BDIM; bb++) {
        const float* yb = (const float*)sY4[bb];
        float z0 = sbz[o], z1 = z0, h0 = sbh[o], h1 = h0;
#pragma unroll
        for (int f = 0; f < FDIM; f++) {
            float ya = yb[f * TDIM + t0];
            float yc = yb[f * TDIM + t1];
            z0 += ya * wzr[f]; h0 += ya * whr[f];
            z1 += yc * wzr[f]; h1 += yc * whr[f];
        }
        float Z0 = 1.f / (1.f + expf(-z0));
        float Z1 = 1.f / (1.f + expf(-z1));
        float H0v = tanhf(h0);
        float H1v = tanhf(h1);
        float contrib = p0 * (1.f - Z0) * H0v + p1 * (1.f - Z1) * H1v;
        atomicAdd(&sAcc[bb][o], contrib);
    }
    __syncthreads();

    // ---- Phase 3: readout ----
    if (tid < BDIM * TDIM) {
        int ob = tid / TDIM, j = tid - ob * TDIM;
        float v = sbout[j];
#pragma unroll
        for (int o2 = 0; o2 < ODIM; o2++) {
            float a = sAcc[ob][o2];
            a = a > 0.f ? a : 0.f;
            v += a * sWout[o2 * TDIM + j];
        }
        out[(unsigned)(ob * N + n) * TDIM + j] = v;
    }
}

extern "C" void kernel_launch(void* const* d_in, const int* in_sizes, int n_in,
                              void* d_out, int out_size, void* d_ws, size_t ws_size,
                              hipStream_t stream) {
    const float* X    = (const float*)d_in[0];
    const int*   ei   = (const int*)d_in[1];
    const float* Wg_z = (const float*)d_in[2];
    const float* bg_z = (const float*)d_in[3];
    const float* Wg_h = (const float*)d_in[6];
    const float* bg_h = (const float*)d_in[7];
    const float* Wl_z = (const float*)d_in[8];
    const float* bl_z = (const float*)d_in[9];
    const float* Wl_h = (const float*)d_in[12];
    const float* bl_h = (const float*)d_in[13];
    const float* att  = (const float*)d_in[14];
    const float* Wout = (const float*)d_in[15];
    const float* bout = (const float*)d_in[16];
    float* out = (float*)d_out;

    const int E = in_sizes[1] / 2;
    const int N = in_sizes[0] / (BDIM * FDIM * TDIM);

    char* wp = (char*)d_ws;
    int* counts   = (int*)wp;   wp += (size_t)N * 4;
    int* fill     = (int*)wp;   wp += (size_t)N * 4;
    int* offs     = (int*)wp;   wp += (size_t)(N + 4) * 4;
    float* dis    = (float*)wp; wp += (size_t)N * 4;
    int* csr_src  = (int*)wp;   wp += (size_t)E * 4;
    float* csr_nm = (float*)wp; wp += (size_t)E * 4;
    float* Wz     = (float*)wp; wp += FDIM * ODIM * 4;
    float* Wh     = (float*)wp; wp += FDIM * ODIM * 4;
    float* bz     = (float*)wp; wp += ODIM * 4;
    float* bh     = (float*)wp; wp += ODIM * 4;
    float* probs  = (float*)wp; wp += 16 * 4;

    hipMemsetAsync(counts, 0, (size_t)2 * N * 4, stream);  // counts + fill (adjacent)

    k_prep<<<1, 256, 0, stream>>>(Wg_z, bg_z, Wl_z, bl_z, Wg_h, bg_h, Wl_h, bl_h,
                                  att, Wz, bz, Wh, bh, probs);
    k_count<<<(E + 255) / 256, 256, 0, stream>>>(ei + E, counts, E);
    k_scan<<<1, 256, 0, stream>>>(counts, offs, dis, N);
    k_scatter<<<(E + 255) / 256, 256, 0, stream>>>(ei, ei + E, offs, fill, dis,
                                                   csr_src, csr_nm, E);
    k_main<<<N, 384, 0, stream>>>(X, offs, csr_src, csr_nm, dis, Wz, bz, Wh, bh,
                                  probs, Wout, bout, out, N);
}

// Round 2
// 1129.435 us; speedup vs baseline: 1.4664x; 1.4664x over previous
//
#include <hip/hip_runtime.h>
#include <hip/hip_bf16.h>

// TemporalGNN: reference's GRU uses H0=zeros every step => R dead, steps independent.
// out[b,n,:] = relu( sum_t p_t * (1-Z)*Ht ) @ W_out + b_out
//   Z  = sigmoid( Y_t @ (Wg_z@Wl_z[:64]) + (bg_z@Wl_z[:64] + bl_z) )
//   Ht = tanh   ( Y_t @ (Wg_h@Wl_h[:64]) + (bg_h@Wl_h[:64] + bl_h) )
//   Y_t = normalized-adjacency aggregation of X[...,t] in F=32 space.

#define FDIM 32
#define TDIM 12
#define ODIM 64
#define BDIM 4
#define ECHUNK 96

__global__ void k_count(const int* __restrict__ dst, int* __restrict__ counts, int E) {
    int e = blockIdx.x * 256 + threadIdx.x;
    if (e < E) atomicAdd(&counts[dst[e]], 1);
}

// 1024-thread single-block scan, wave-shuffle based (few barriers).
__global__ __launch_bounds__(1024) void k_scan(const int* __restrict__ counts,
                                               int* __restrict__ offsets,
                                               float* __restrict__ dis, int N) {
    __shared__ int wsum[16];
    __shared__ int sCarry;
    const int tid = threadIdx.x;
    const int lane = tid & 63;
    const int wv = tid >> 6;
    if (tid == 0) sCarry = 0;
    __syncthreads();
    for (int base = 0; base < N; base += 1024) {
        int i = base + tid;
        int v = (i < N) ? counts[i] : 0;
        int s = v;  // inclusive wave scan
        for (int off = 1; off < 64; off <<= 1) {
            int t = __shfl_up(s, off, 64);
            if (lane >= off) s += t;
        }
        if (lane == 63) wsum[wv] = s;
        __syncthreads();
        if (wv == 0 && lane < 16) {
            int ws = wsum[lane];
            for (int off = 1; off < 16; off <<= 1) {
                int t = __shfl_up(ws, off, 64);
                if (lane >= off) ws += t;
            }
            wsum[lane] = ws;  // inclusive wave-sum scan
        }
        __syncthreads();
        int carry = sCarry;
        int wpre = (wv > 0) ? wsum[wv - 1] : 0;
        if (i < N) {
            offsets[i] = carry + wpre + s - v;       // exclusive
            dis[i] = 1.0f / sqrtf((float)(v + 1));   // deg^{-1/2}
        }
        __syncthreads();
        if (tid == 0) sCarry = carry + wsum[15];
        __syncthreads();
    }
    if (tid == 0) offsets[N] = sCarry;
}

__global__ void k_scatter(const int* __restrict__ src, const int* __restrict__ dst,
                          const int* __restrict__ offsets, int* __restrict__ fill,
                          const float* __restrict__ dis,
                          int2* __restrict__ csr, int E) {
    int e = blockIdx.x * 256 + threadIdx.x;
    if (e < E) {
        int s = src[e], d = dst[e];
        int pos = offsets[d] + atomicAdd(&fill[d], 1);
        csr[pos] = make_int2(s, __float_as_int(dis[s] * dis[d]));
    }
}

// Fold Wg@Wl_top, biases, and softmax(att) once per launch.
__global__ void k_prep(const float* __restrict__ Wg_z, const float* __restrict__ bg_z,
                       const float* __restrict__ Wl_z, const float* __restrict__ bl_z,
                       const float* __restrict__ Wg_h, const float* __restrict__ bg_h,
                       const float* __restrict__ Wl_h, const float* __restrict__ bl_h,
                       const float* __restrict__ att,
                       float* __restrict__ Wz, float* __restrict__ bz,
                       float* __restrict__ Wh, float* __restrict__ bh,
                       float* __restrict__ probs) {
    int tid = threadIdx.x;
    for (int i = tid; i < FDIM * ODIM; i += 256) {
        int f = i >> 6, o = i & 63;
        float az = 0.f, ah = 0.f;
        for (int k = 0; k < ODIM; k++) {
            az += Wg_z[f * ODIM + k] * Wl_z[k * ODIM + o];
            ah += Wg_h[f * ODIM + k] * Wl_h[k * ODIM + o];
        }
        Wz[i] = az;
        Wh[i] = ah;
    }
    if (tid < ODIM) {
        float az = bl_z[tid], ah = bl_h[tid];
        for (int k = 0; k < ODIM; k++) {
            az += bg_z[k] * Wl_z[k * ODIM + tid];
            ah += bg_h[k] * Wl_h[k * ODIM + tid];
        }
        bz[tid] = az;
        bh[tid] = ah;
    }
    if (tid == 0) {
        float m = -1e30f;
        for (int t = 0; t < TDIM; t++) m = fmaxf(m, att[t]);
        float e[TDIM], s = 0.f;
        for (int t = 0; t < TDIM; t++) { e[t] = expf(att[t] - m); s += e[t]; }
        for (int t = 0; t < TDIM; t++) probs[t] = e[t] / s;
    }
}

// One workgroup per node n; 384 threads = 6 waves.
// Phase 1: stage packed edges to LDS, then 4-way-unrolled float4 gathers
//          (4 independent accumulators -> 4 loads in flight per thread).
// Phase 2: GEMV 32->64 for z/h gates, all t at once, weights in registers
//          (read straight from global; L2-hot, no LDS staging).
// Phase 3: ReLU + 64->12 readout.
__global__ __launch_bounds__(384) void k_main(
    const float* __restrict__ X, const int* __restrict__ offsets,
    const int2* __restrict__ csr, const float* __restrict__ dis,
    const float* __restrict__ Wz, const float* __restrict__ bz,
    const float* __restrict__ Wh, const float* __restrict__ bh,
    const float* __restrict__ probs, const float* __restrict__ Wout,
    const float* __restrict__ bout, float* __restrict__ out, int N) {
    const int n = blockIdx.x;
    const int tid = threadIdx.x;

    __shared__ float4 sY4[BDIM][96];   // [b][f*T+t as float4]  6 KiB
    __shared__ float sAcc[BDIM][ODIM]; // 1 KiB
    __shared__ int2 sEdge[ECHUNK];     // 768 B

    if (tid < BDIM * ODIM) ((float*)sAcc)[tid] = 0.f;

    const int beg = offsets[n], end = offsets[n + 1];
    const float dn = dis[n];
    const float snorm = dn * dn;

    // ---- Phase 1: aggregation (thread owns batch b, float4-chunk q) ----
    const int b = tid / 96;
    const int q = tid - b * 96;
    const float4* __restrict__ Xq = (const float4*)X;
    float4 a0 = Xq[(unsigned)(b * N + n) * 96u + q];
    a0.x *= snorm; a0.y *= snorm; a0.z *= snorm; a0.w *= snorm;
    float4 a1 = make_float4(0.f, 0.f, 0.f, 0.f);
    float4 a2 = make_float4(0.f, 0.f, 0.f, 0.f);
    float4 a3 = make_float4(0.f, 0.f, 0.f, 0.f);

    for (int base = beg; base < end; base += ECHUNK) {
        const int cnt = min(ECHUNK, end - base);
        __syncthreads();
        for (int i = tid; i < cnt; i += 384) sEdge[i] = csr[base + i];
        __syncthreads();
        int j = 0;
        for (; j + 4 <= cnt; j += 4) {
            const int2 e0 = sEdge[j], e1 = sEdge[j + 1], e2 = sEdge[j + 2], e3 = sEdge[j + 3];
            const float4 v0 = Xq[(unsigned)(b * N + e0.x) * 96u + q];
            const float4 v1 = Xq[(unsigned)(b * N + e1.x) * 96u + q];
            const float4 v2 = Xq[(unsigned)(b * N + e2.x) * 96u + q];
            const float4 v3 = Xq[(unsigned)(b * N + e3.x) * 96u + q];
            const float n0 = __int_as_float(e0.y), n1 = __int_as_float(e1.y);
            const float n2 = __int_as_float(e2.y), n3 = __int_as_float(e3.y);
            a0.x += n0 * v0.x; a0.y += n0 * v0.y; a0.z += n0 * v0.z; a0.w += n0 * v0.w;
            a1.x += n1 * v1.x; a1.y += n1 * v1.y; a1.z += n1 * v1.z; a1.w += n1 * v1.w;
            a2.x += n2 * v2.x; a2.y += n2 * v2.y; a2.z += n2 * v2.z; a2.w += n2 * v2.w;
            a3.x += n3 * v3.x; a3.y += n3 * v3.y; a3.z += n3 * v3.z; a3.w += n3 * v3.w;
        }
        for (; j < cnt; j++) {
            const int2 e = sEdge[j];
            const float4 v = Xq[(unsigned)(b * N + e.x) * 96u + q];
            const float nm = __int_as_float(e.y);
            a0.x += nm * v.x; a0.y += nm * v.y; a0.z += nm * v.z; a0.w += nm * v.w;
        }
    }
    a0.x += (a1.x + a2.x) + a3.x;
    a0.y += (a1.y + a2.y) + a3.y;
    a0.z += (a1.z + a2.z) + a3.z;
    a0.w += (a1.w + a2.w) + a3.w;
    sY4[b][q] = a0;

    // Preload gate weights into registers (independent of LDS; overlaps barrier).
    const int o = tid & 63;
    const int w = tid >> 6;
    float wzr[FDIM], whr[FDIM];
#pragma unroll
    for (int f = 0; f < FDIM; f++) {
        wzr[f] = Wz[f * ODIM + o];
        whr[f] = Wh[f * ODIM + o];
    }
    const float bzo = bz[o], bho = bh[o];
    const int t0 = w, t1 = w + 6;
    const float p0 = probs[t0], p1 = probs[t1];
    __syncthreads();

    // ---- Phase 2: gates. thread -> (o, t in {w, w+6}) ----
#pragma unroll
    for (int bb = 0; bb < BDIM; bb++) {
        const float* yb = (const float*)sY4[bb];
        float z0 = bzo, z1 = bzo, h0 = bho, h1 = bho;
#pragma unroll
        for (int f = 0; f < FDIM; f++) {
            float ya = yb[f * TDIM + t0];
            float yc = yb[f * TDIM + t1];
            z0 += ya * wzr[f]; h0 += ya * whr[f];
            z1 += yc * wzr[f]; h1 += yc * whr[f];
        }
        float Z0 = 1.f / (1.f + expf(-z0));
        float Z1 = 1.f / (1.f + expf(-z1));
        float H0v = tanhf(h0);
        float H1v = tanhf(h1);
        float contrib = p0 * (1.f - Z0) * H0v + p1 * (1.f - Z1) * H1v;
        atomicAdd(&sAcc[bb][o], contrib);
    }
    __syncthreads();

    // ---- Phase 3: readout ----
    if (tid < BDIM * TDIM) {
        int ob = tid / TDIM, jj = tid - ob * TDIM;
        float v = bout[jj];
#pragma unroll
        for (int o2 = 0; o2 < ODIM; o2++) {
            float a = sAcc[ob][o2];
            v += fmaxf(a, 0.f) * Wout[o2 * TDIM + jj];
        }
        out[(unsigned)(ob * N + n) * TDIM + jj] = v;
    }
}

extern "C" void kernel_launch(void* const* d_in, const int* in_sizes, int n_in,
                              void* d_out, int out_size, void* d_ws, size_t ws_size,
                              hipStream_t stream) {
    const float* X    = (const float*)d_in[0];
    const int*   ei   = (const int*)d_in[1];
    const float* Wg_z = (const float*)d_in[2];
    const float* bg_z = (const float*)d_in[3];
    const float* Wg_h = (const float*)d_in[6];
    const float* bg_h = (const float*)d_in[7];
    const float* Wl_z = (const float*)d_in[8];
    const float* bl_z = (const float*)d_in[9];
    const float* Wl_h = (const float*)d_in[12];
    const float* bl_h = (const float*)d_in[13];
    const float* att  = (const float*)d_in[14];
    const float* Wout = (const float*)d_in[15];
    const float* bout = (const float*)d_in[16];
    float* out = (float*)d_out;

    const int E = in_sizes[1] / 2;
    const int N = in_sizes[0] / (BDIM * FDIM * TDIM);

    char* wp = (char*)d_ws;
    int* counts   = (int*)wp;   wp += (size_t)N * 4;
    int* fill     = (int*)wp;   wp += (size_t)N * 4;
    int* offs     = (int*)wp;   wp += (size_t)(N + 4) * 4;
    float* dis    = (float*)wp; wp += (size_t)N * 4;
    int2* csr     = (int2*)wp;  wp += (size_t)E * 8;
    float* Wz     = (float*)wp; wp += FDIM * ODIM * 4;
    float* Wh     = (float*)wp; wp += FDIM * ODIM * 4;
    float* bz     = (float*)wp; wp += ODIM * 4;
    float* bh     = (float*)wp; wp += ODIM * 4;
    float* probs  = (float*)wp; wp += 16 * 4;

    hipMemsetAsync(counts, 0, (size_t)2 * N * 4, stream);  // counts + fill (adjacent)

    k_prep<<<1, 256, 0, stream>>>(Wg_z, bg_z, Wl_z, bl_z, Wg_h, bg_h, Wl_h, bl_h,
                                  att, Wz, bz, Wh, bh, probs);
    k_count<<<(E + 255) / 256, 256, 0, stream>>>(ei + E, counts, E);
    k_scan<<<1, 1024, 0, stream>>>(counts, offs, dis, N);
    k_scatter<<<(E + 255) / 256, 256, 0, stream>>>(ei, ei + E, offs, fill, dis, csr, E);
    k_main<<<N, 384, 0, stream>>>(X, offs, csr, dis, Wz, bz, Wh, bh,
                                  probs, Wout, bout, out, N);
}